// Round 1
// baseline (107.323 us; speedup 1.0000x reference)
//
#include <hip/hip_runtime.h>
#include <math.h>

#define PCNT 1024
#define HH 160
#define WW 160
#define NPIX (HH * WW)

// 12 floats per gaussian: {px,py,conA,conB}, {conC,op,r,g}, {b,0,0,0}
struct __align__(16) GP {
    float px, py, ca, cb;
    float cc, op, cr, cg;
    float cbl, p0, p1, p2;
};

__global__ __launch_bounds__(256) void k_pre(
    const float* __restrict__ means, const float* __restrict__ cols,
    const float* __restrict__ ops, const float* __restrict__ scales,
    const float* __restrict__ rots, const float* __restrict__ vm,
    const float* __restrict__ pm, float* __restrict__ radii_out,
    GP* __restrict__ params, unsigned long long* __restrict__ keys)
{
    int i = blockIdx.x * blockDim.x + threadIdx.x;
    if (i >= PCNT) return;

    float mx = means[3 * i], my = means[3 * i + 1], mz = means[3 * i + 2];

    // t = V @ [m,1]
    float t0 = vm[0] * mx + vm[1] * my + vm[2] * mz + vm[3];
    float t1 = vm[4] * mx + vm[5] * my + vm[6] * mz + vm[7];
    float t2 = vm[8] * mx + vm[9] * my + vm[10] * mz + vm[11];
    bool depth_ok = t2 > 0.2f;

    // p_hom = Proj @ [m,1]
    float ph0 = pm[0] * mx + pm[1] * my + pm[2] * mz + pm[3];
    float ph1 = pm[4] * mx + pm[5] * my + pm[6] * mz + pm[7];
    float ph3 = pm[12] * mx + pm[13] * my + pm[14] * mz + pm[15];
    float pw = 1.0f / (ph3 + 1e-7f);
    float px = ((ph0 * pw + 1.0f) * (float)WW - 1.0f) * 0.5f;
    float py = ((ph1 * pw + 1.0f) * (float)HH - 1.0f) * 0.5f;

    // quaternion -> rotation
    float qr = rots[4 * i], qx = rots[4 * i + 1], qy = rots[4 * i + 2], qz = rots[4 * i + 3];
    float R00 = 1.f - 2.f * (qy * qy + qz * qz), R01 = 2.f * (qx * qy - qr * qz), R02 = 2.f * (qx * qz + qr * qy);
    float R10 = 2.f * (qx * qy + qr * qz), R11 = 1.f - 2.f * (qx * qx + qz * qz), R12 = 2.f * (qy * qz - qr * qx);
    float R20 = 2.f * (qx * qz - qr * qy), R21 = 2.f * (qy * qz + qr * qx), R22 = 1.f - 2.f * (qx * qx + qy * qy);

    float s0 = scales[3 * i], s1 = scales[3 * i + 1], s2 = scales[3 * i + 2];
    // M = R * s (column scaling), cov3D = M @ M^T (symmetric)
    float M00 = R00 * s0, M01 = R01 * s1, M02 = R02 * s2;
    float M10 = R10 * s0, M11 = R11 * s1, M12 = R12 * s2;
    float M20 = R20 * s0, M21 = R21 * s1, M22 = R22 * s2;
    float c00 = M00 * M00 + M01 * M01 + M02 * M02;
    float c01 = M00 * M10 + M01 * M11 + M02 * M12;
    float c02 = M00 * M20 + M01 * M21 + M02 * M22;
    float c11 = M10 * M10 + M11 * M11 + M12 * M12;
    float c12 = M10 * M20 + M11 * M21 + M12 * M22;
    float c22 = M20 * M20 + M21 * M21 + M22 * M22;

    const float fx = (float)WW / (2.0f * 0.5f); // 160
    const float fy = (float)HH / (2.0f * 0.5f); // 160
    const float limx = 1.3f * 0.5f, limy = 1.3f * 0.5f;
    float txz = fminf(limx, fmaxf(-limx, t0 / t2)) * t2;
    float tyz = fminf(limy, fmaxf(-limy, t1 / t2)) * t2;
    float J00 = fx / t2, J02 = -fx * txz / (t2 * t2);
    float J11 = fy / t2, J12 = -fy * tyz / (t2 * t2);

    // T = J @ Wm   (Wm = vm[:3,:3]); J01 = J10 = 0
    float T00 = J00 * vm[0] + J02 * vm[8];
    float T01 = J00 * vm[1] + J02 * vm[9];
    float T02 = J00 * vm[2] + J02 * vm[10];
    float T10 = J11 * vm[4] + J12 * vm[8];
    float T11 = J11 * vm[5] + J12 * vm[9];
    float T12 = J11 * vm[6] + J12 * vm[10];

    // u = T @ cov3D ; cov2 = u @ T^T
    float u00 = T00 * c00 + T01 * c01 + T02 * c02;
    float u01 = T00 * c01 + T01 * c11 + T02 * c12;
    float u02 = T00 * c02 + T01 * c12 + T02 * c22;
    float u10 = T10 * c00 + T11 * c01 + T12 * c02;
    float u11 = T10 * c01 + T11 * c11 + T12 * c12;
    float u12 = T10 * c02 + T11 * c12 + T12 * c22;
    float a  = u00 * T00 + u01 * T01 + u02 * T02 + 0.3f;
    float bb = u00 * T10 + u01 * T11 + u02 * T12;
    float cc = u10 * T10 + u11 * T11 + u12 * T12 + 0.3f;

    float det = a * cc - bb * bb;
    bool det_ok = det > 0.0f;
    float inv_det = det_ok ? 1.0f / det : 0.0f;
    float conA = cc * inv_det, conB = -bb * inv_det, conC = a * inv_det;
    float mid = 0.5f * (a + cc);
    float lam1 = mid + sqrtf(fmaxf(0.1f, mid * mid - det));
    float radius = ceilf(3.0f * sqrtf(lam1));
    bool valid = depth_ok && det_ok;

    radii_out[i] = valid ? (float)(int)radius : 0.0f;

    GP g;
    if (valid) {
        g.px = px; g.py = py; g.ca = conA; g.cb = conB;
        g.cc = conC; g.op = ops[i];
        g.cr = cols[3 * i]; g.cg = cols[3 * i + 1]; g.cbl = cols[3 * i + 2];
        g.p0 = 0.f; g.p1 = 0.f; g.p2 = 0.f;
    } else {
        g.px = 0.f; g.py = 0.f; g.ca = 0.f; g.cb = 0.f;
        g.cc = 0.f; g.op = 0.f; g.cr = 0.f; g.cg = 0.f;
        g.cbl = 0.f; g.p0 = 0.f; g.p1 = 0.f; g.p2 = 0.f;
    }
    params[i] = g;

    // positive floats (and +inf) sort correctly by bit pattern
    unsigned int kb = valid ? __float_as_uint(t2) : 0x7f800000u;
    keys[i] = ((unsigned long long)kb << 32) | (unsigned int)i;
}

__global__ __launch_bounds__(1024) void k_sort(
    const unsigned long long* __restrict__ keys_in,
    const float4* __restrict__ pin, float4* __restrict__ pout)
{
    __shared__ unsigned long long k[PCNT];
    int t = threadIdx.x;
    k[t] = keys_in[t];
    __syncthreads();
    for (int size = 2; size <= PCNT; size <<= 1) {
        for (int stride = size >> 1; stride > 0; stride >>= 1) {
            int j = t ^ stride;
            if (j > t) {
                unsigned long long a = k[t], b = k[j];
                bool desc = (t & size) != 0;
                bool sw = desc ? (a < b) : (a > b);
                if (sw) { k[t] = b; k[j] = a; }
            }
            __syncthreads();
        }
    }
    int idx = (int)(k[t] & 0xffffffffu);
    pout[t * 3 + 0] = pin[idx * 3 + 0];
    pout[t * 3 + 1] = pin[idx * 3 + 1];
    pout[t * 3 + 2] = pin[idx * 3 + 2];
}

__global__ __launch_bounds__(256) void k_render(
    const float4* __restrict__ sorted, const float* __restrict__ bg,
    float* __restrict__ out)
{
    __shared__ float4 sp[PCNT * 3];
    for (int i = threadIdx.x; i < PCNT * 3; i += 256) sp[i] = sorted[i];
    __syncthreads();

    int pix = blockIdx.x * 256 + threadIdx.x;
    float fxp = (float)(pix % WW);
    float fyp = (float)(pix / WW);

    float T = 1.0f, C0 = 0.f, C1 = 0.f, C2 = 0.f;
    for (int g = 0; g < PCNT; ++g) {
        float4 v0 = sp[3 * g + 0];   // px,py,ca,cb
        float4 v1 = sp[3 * g + 1];   // cc,op,r,g
        float4 v2 = sp[3 * g + 2];   // b,-,-,-
        float dx = v0.x - fxp, dy = v0.y - fyp;
        float power = -0.5f * (v0.z * dx * dx + v1.x * dy * dy) - v0.w * dx * dy;
        float alpha = fminf(0.99f, v1.y * expf(power));
        if (power > 0.0f || alpha < (1.0f / 255.0f)) alpha = 0.0f;
        float w = alpha * T;
        C0 = fmaf(w, v1.z, C0);
        C1 = fmaf(w, v1.w, C1);
        C2 = fmaf(w, v2.x, C2);
        T *= (1.0f - alpha);
    }
    out[pix]            = C0 + T * bg[0];
    out[NPIX + pix]     = C1 + T * bg[1];
    out[2 * NPIX + pix] = C2 + T * bg[2];
}

extern "C" void kernel_launch(void* const* d_in, const int* in_sizes, int n_in,
                              void* d_out, int out_size, void* d_ws, size_t ws_size,
                              hipStream_t stream) {
    const float* means  = (const float*)d_in[0];
    // d_in[1] = means2D (unused)
    const float* cols   = (const float*)d_in[2];
    const float* ops    = (const float*)d_in[3];
    const float* scales = (const float*)d_in[4];
    const float* rots   = (const float*)d_in[5];
    const float* bg     = (const float*)d_in[6];
    const float* vm     = (const float*)d_in[7];
    const float* pm     = (const float*)d_in[8];
    // d_in[9] = campos (unused)

    float* out = (float*)d_out;   // [3*NPIX color][PCNT radii-as-float]

    GP* params = (GP*)d_ws;                                   // PCNT * 48B
    GP* sortedp = params + PCNT;                              // PCNT * 48B
    unsigned long long* keys = (unsigned long long*)(sortedp + PCNT); // PCNT * 8B

    k_pre<<<PCNT / 256, 256, 0, stream>>>(means, cols, ops, scales, rots, vm, pm,
                                          out + 3 * NPIX, params, keys);
    k_sort<<<1, PCNT, 0, stream>>>(keys, (const float4*)params, (float4*)sortedp);
    k_render<<<NPIX / 256, 256, 0, stream>>>((const float4*)sortedp, bg, out);
}

// Round 2
// 53.544 us; speedup vs baseline: 2.0044x; 2.0044x over previous
//
#include <hip/hip_runtime.h>
#include <math.h>

#define PCNT 1024
#define HH 160
#define WW 160
#define NPIX (HH * WW)
#define SEG 16
#define GPSEG (PCNT / SEG)   // 64 gaussians per segment

// 12 floats per gaussian: {px,py,conA,conB}, {conC,op,r,g}, {b,0,0,0}
struct __align__(16) GP {
    float px, py, ca, cb;
    float cc, op, cr, cg;
    float cbl, p0, p1, p2;
};

__global__ __launch_bounds__(256) void k_pre(
    const float* __restrict__ means, const float* __restrict__ cols,
    const float* __restrict__ ops, const float* __restrict__ scales,
    const float* __restrict__ rots, const float* __restrict__ vm,
    const float* __restrict__ pm, float* __restrict__ radii_out,
    GP* __restrict__ params, unsigned long long* __restrict__ keys)
{
    int i = blockIdx.x * blockDim.x + threadIdx.x;
    if (i >= PCNT) return;

    float mx = means[3 * i], my = means[3 * i + 1], mz = means[3 * i + 2];

    float t0 = vm[0] * mx + vm[1] * my + vm[2] * mz + vm[3];
    float t1 = vm[4] * mx + vm[5] * my + vm[6] * mz + vm[7];
    float t2 = vm[8] * mx + vm[9] * my + vm[10] * mz + vm[11];
    bool depth_ok = t2 > 0.2f;

    float ph0 = pm[0] * mx + pm[1] * my + pm[2] * mz + pm[3];
    float ph1 = pm[4] * mx + pm[5] * my + pm[6] * mz + pm[7];
    float ph3 = pm[12] * mx + pm[13] * my + pm[14] * mz + pm[15];
    float pw = 1.0f / (ph3 + 1e-7f);
    float px = ((ph0 * pw + 1.0f) * (float)WW - 1.0f) * 0.5f;
    float py = ((ph1 * pw + 1.0f) * (float)HH - 1.0f) * 0.5f;

    float qr = rots[4 * i], qx = rots[4 * i + 1], qy = rots[4 * i + 2], qz = rots[4 * i + 3];
    float R00 = 1.f - 2.f * (qy * qy + qz * qz), R01 = 2.f * (qx * qy - qr * qz), R02 = 2.f * (qx * qz + qr * qy);
    float R10 = 2.f * (qx * qy + qr * qz), R11 = 1.f - 2.f * (qx * qx + qz * qz), R12 = 2.f * (qy * qz - qr * qx);
    float R20 = 2.f * (qx * qz - qr * qy), R21 = 2.f * (qy * qz + qr * qx), R22 = 1.f - 2.f * (qx * qx + qy * qy);

    float s0 = scales[3 * i], s1 = scales[3 * i + 1], s2 = scales[3 * i + 2];
    float M00 = R00 * s0, M01 = R01 * s1, M02 = R02 * s2;
    float M10 = R10 * s0, M11 = R11 * s1, M12 = R12 * s2;
    float M20 = R20 * s0, M21 = R21 * s1, M22 = R22 * s2;
    float c00 = M00 * M00 + M01 * M01 + M02 * M02;
    float c01 = M00 * M10 + M01 * M11 + M02 * M12;
    float c02 = M00 * M20 + M01 * M21 + M02 * M22;
    float c11 = M10 * M10 + M11 * M11 + M12 * M12;
    float c12 = M10 * M20 + M11 * M21 + M12 * M22;
    float c22 = M20 * M20 + M21 * M21 + M22 * M22;

    const float fx = 160.0f, fy = 160.0f;
    const float limx = 0.65f, limy = 0.65f;
    float txz = fminf(limx, fmaxf(-limx, t0 / t2)) * t2;
    float tyz = fminf(limy, fmaxf(-limy, t1 / t2)) * t2;
    float J00 = fx / t2, J02 = -fx * txz / (t2 * t2);
    float J11 = fy / t2, J12 = -fy * tyz / (t2 * t2);

    float T00 = J00 * vm[0] + J02 * vm[8];
    float T01 = J00 * vm[1] + J02 * vm[9];
    float T02 = J00 * vm[2] + J02 * vm[10];
    float T10 = J11 * vm[4] + J12 * vm[8];
    float T11 = J11 * vm[5] + J12 * vm[9];
    float T12 = J11 * vm[6] + J12 * vm[10];

    float u00 = T00 * c00 + T01 * c01 + T02 * c02;
    float u01 = T00 * c01 + T01 * c11 + T02 * c12;
    float u02 = T00 * c02 + T01 * c12 + T02 * c22;
    float u10 = T10 * c00 + T11 * c01 + T12 * c02;
    float u11 = T10 * c01 + T11 * c11 + T12 * c12;
    float u12 = T10 * c02 + T11 * c12 + T12 * c22;
    float a  = u00 * T00 + u01 * T01 + u02 * T02 + 0.3f;
    float bb = u00 * T10 + u01 * T11 + u02 * T12;
    float cc = u10 * T10 + u11 * T11 + u12 * T12 + 0.3f;

    float det = a * cc - bb * bb;
    bool det_ok = det > 0.0f;
    float inv_det = det_ok ? 1.0f / det : 0.0f;
    float conA = cc * inv_det, conB = -bb * inv_det, conC = a * inv_det;
    float mid = 0.5f * (a + cc);
    float lam1 = mid + sqrtf(fmaxf(0.1f, mid * mid - det));
    float radius = ceilf(3.0f * sqrtf(lam1));
    bool valid = depth_ok && det_ok;

    radii_out[i] = valid ? (float)(int)radius : 0.0f;

    GP g;
    if (valid) {
        g.px = px; g.py = py; g.ca = conA; g.cb = conB;
        g.cc = conC; g.op = ops[i];
        g.cr = cols[3 * i]; g.cg = cols[3 * i + 1]; g.cbl = cols[3 * i + 2];
        g.p0 = 0.f; g.p1 = 0.f; g.p2 = 0.f;
    } else {
        g.px = 0.f; g.py = 0.f; g.ca = 0.f; g.cb = 0.f;
        g.cc = 0.f; g.op = 0.f; g.cr = 0.f; g.cg = 0.f;
        g.cbl = 0.f; g.p0 = 0.f; g.p1 = 0.f; g.p2 = 0.f;
    }
    params[i] = g;

    unsigned int kb = valid ? __float_as_uint(t2) : 0x7f800000u;
    keys[i] = ((unsigned long long)kb << 32) | (unsigned int)i;
}

__global__ __launch_bounds__(1024) void k_sort(
    const unsigned long long* __restrict__ keys_in,
    const float4* __restrict__ pin, float4* __restrict__ pout)
{
    __shared__ unsigned long long k[PCNT];
    int t = threadIdx.x;
    k[t] = keys_in[t];
    __syncthreads();
    for (int size = 2; size <= PCNT; size <<= 1) {
        for (int stride = size >> 1; stride > 0; stride >>= 1) {
            int j = t ^ stride;
            if (j > t) {
                unsigned long long a = k[t], b = k[j];
                bool desc = (t & size) != 0;
                bool sw = desc ? (a < b) : (a > b);
                if (sw) { k[t] = b; k[j] = a; }
            }
            __syncthreads();
        }
    }
    int idx = (int)(k[t] & 0xffffffffu);
    pout[t * 3 + 0] = pin[idx * 3 + 0];
    pout[t * 3 + 1] = pin[idx * 3 + 1];
    pout[t * 3 + 2] = pin[idx * 3 + 2];
}

// One block = (256 pixels) x (one 64-gaussian segment). Writes (C0,C1,C2,T).
__global__ __launch_bounds__(256) void k_render_part(
    const float4* __restrict__ sorted, float4* __restrict__ part)
{
    __shared__ float4 sp[GPSEG * 3];
    int seg = blockIdx.y;
    for (int i = threadIdx.x; i < GPSEG * 3; i += 256)
        sp[i] = sorted[seg * GPSEG * 3 + i];
    __syncthreads();

    int pix = blockIdx.x * 256 + threadIdx.x;
    float fxp = (float)(pix % WW);
    float fyp = (float)(pix / WW);

    float T = 1.0f, C0 = 0.f, C1 = 0.f, C2 = 0.f;
    #pragma unroll 4
    for (int g = 0; g < GPSEG; ++g) {
        float4 v0 = sp[3 * g + 0];   // px,py,ca,cb
        float4 v1 = sp[3 * g + 1];   // cc,op,r,g
        float4 v2 = sp[3 * g + 2];   // b,-,-,-
        float dx = v0.x - fxp, dy = v0.y - fyp;
        float power = -0.5f * (v0.z * dx * dx + v1.x * dy * dy) - v0.w * dx * dy;
        float alpha = fminf(0.99f, v1.y * expf(power));
        if (power > 0.0f || alpha < (1.0f / 255.0f)) alpha = 0.0f;
        float w = alpha * T;
        C0 = fmaf(w, v1.z, C0);
        C1 = fmaf(w, v1.w, C1);
        C2 = fmaf(w, v2.x, C2);
        T *= (1.0f - alpha);
    }
    part[seg * NPIX + pix] = make_float4(C0, C1, C2, T);
}

__global__ __launch_bounds__(256) void k_combine(
    const float4* __restrict__ part, const float* __restrict__ bg,
    float* __restrict__ out)
{
    int pix = blockIdx.x * 256 + threadIdx.x;
    float T = 1.0f, C0 = 0.f, C1 = 0.f, C2 = 0.f;
    #pragma unroll
    for (int s = 0; s < SEG; ++s) {
        float4 v = part[s * NPIX + pix];
        C0 = fmaf(T, v.x, C0);
        C1 = fmaf(T, v.y, C1);
        C2 = fmaf(T, v.z, C2);
        T *= v.w;
    }
    out[pix]            = C0 + T * bg[0];
    out[NPIX + pix]     = C1 + T * bg[1];
    out[2 * NPIX + pix] = C2 + T * bg[2];
}

extern "C" void kernel_launch(void* const* d_in, const int* in_sizes, int n_in,
                              void* d_out, int out_size, void* d_ws, size_t ws_size,
                              hipStream_t stream) {
    const float* means  = (const float*)d_in[0];
    const float* cols   = (const float*)d_in[2];
    const float* ops    = (const float*)d_in[3];
    const float* scales = (const float*)d_in[4];
    const float* rots   = (const float*)d_in[5];
    const float* bg     = (const float*)d_in[6];
    const float* vm     = (const float*)d_in[7];
    const float* pm     = (const float*)d_in[8];

    float* out = (float*)d_out;   // [3*NPIX color][PCNT radii-as-float]

    GP* params  = (GP*)d_ws;                                        // PCNT*48B
    GP* sortedp = params + PCNT;                                    // PCNT*48B
    unsigned long long* keys = (unsigned long long*)(sortedp + PCNT); // PCNT*8B
    float4* part = (float4*)(keys + PCNT);                          // SEG*NPIX*16B = 6.55MB

    k_pre<<<PCNT / 256, 256, 0, stream>>>(means, cols, ops, scales, rots, vm, pm,
                                          out + 3 * NPIX, params, keys);
    k_sort<<<1, PCNT, 0, stream>>>(keys, (const float4*)params, (float4*)sortedp);
    dim3 grid_rp(NPIX / 256, SEG);
    k_render_part<<<grid_rp, 256, 0, stream>>>((const float4*)sortedp, part);
    k_combine<<<NPIX / 256, 256, 0, stream>>>(part, bg, out);
}

// Round 3
// 42.243 us; speedup vs baseline: 2.5406x; 1.2675x over previous
//
#include <hip/hip_runtime.h>
#include <math.h>

#define PCNT 1024
#define HH 160
#define WW 160
#define NPIX (HH * WW)
#define SEG 16
#define GPSEG (PCNT / SEG)   // 64 gaussians per segment

// 12 floats per gaussian: {px,py,conA,conB}, {conC,op,r,g}, {b,0,0,0}
struct __align__(16) GP {
    float px, py, ca, cb;
    float cc, op, cr, cg;
    float cbl, p0, p1, p2;
};

__global__ __launch_bounds__(256) void k_pre(
    const float* __restrict__ means, const float* __restrict__ cols,
    const float* __restrict__ ops, const float* __restrict__ scales,
    const float* __restrict__ rots, const float* __restrict__ vm,
    const float* __restrict__ pm, float* __restrict__ radii_out,
    GP* __restrict__ params, unsigned long long* __restrict__ keys)
{
    int i = blockIdx.x * blockDim.x + threadIdx.x;
    if (i >= PCNT) return;

    float mx = means[3 * i], my = means[3 * i + 1], mz = means[3 * i + 2];

    float t0 = vm[0] * mx + vm[1] * my + vm[2] * mz + vm[3];
    float t1 = vm[4] * mx + vm[5] * my + vm[6] * mz + vm[7];
    float t2 = vm[8] * mx + vm[9] * my + vm[10] * mz + vm[11];
    bool depth_ok = t2 > 0.2f;

    float ph0 = pm[0] * mx + pm[1] * my + pm[2] * mz + pm[3];
    float ph1 = pm[4] * mx + pm[5] * my + pm[6] * mz + pm[7];
    float ph3 = pm[12] * mx + pm[13] * my + pm[14] * mz + pm[15];
    float pw = 1.0f / (ph3 + 1e-7f);
    float px = ((ph0 * pw + 1.0f) * (float)WW - 1.0f) * 0.5f;
    float py = ((ph1 * pw + 1.0f) * (float)HH - 1.0f) * 0.5f;

    float qr = rots[4 * i], qx = rots[4 * i + 1], qy = rots[4 * i + 2], qz = rots[4 * i + 3];
    float R00 = 1.f - 2.f * (qy * qy + qz * qz), R01 = 2.f * (qx * qy - qr * qz), R02 = 2.f * (qx * qz + qr * qy);
    float R10 = 2.f * (qx * qy + qr * qz), R11 = 1.f - 2.f * (qx * qx + qz * qz), R12 = 2.f * (qy * qz - qr * qx);
    float R20 = 2.f * (qx * qz - qr * qy), R21 = 2.f * (qy * qz + qr * qx), R22 = 1.f - 2.f * (qx * qx + qy * qy);

    float s0 = scales[3 * i], s1 = scales[3 * i + 1], s2 = scales[3 * i + 2];
    float M00 = R00 * s0, M01 = R01 * s1, M02 = R02 * s2;
    float M10 = R10 * s0, M11 = R11 * s1, M12 = R12 * s2;
    float M20 = R20 * s0, M21 = R21 * s1, M22 = R22 * s2;
    float c00 = M00 * M00 + M01 * M01 + M02 * M02;
    float c01 = M00 * M10 + M01 * M11 + M02 * M12;
    float c02 = M00 * M20 + M01 * M21 + M02 * M22;
    float c11 = M10 * M10 + M11 * M11 + M12 * M12;
    float c12 = M10 * M20 + M11 * M21 + M12 * M22;
    float c22 = M20 * M20 + M21 * M21 + M22 * M22;

    const float fx = 160.0f, fy = 160.0f;
    const float limx = 0.65f, limy = 0.65f;
    float txz = fminf(limx, fmaxf(-limx, t0 / t2)) * t2;
    float tyz = fminf(limy, fmaxf(-limy, t1 / t2)) * t2;
    float J00 = fx / t2, J02 = -fx * txz / (t2 * t2);
    float J11 = fy / t2, J12 = -fy * tyz / (t2 * t2);

    float T00 = J00 * vm[0] + J02 * vm[8];
    float T01 = J00 * vm[1] + J02 * vm[9];
    float T02 = J00 * vm[2] + J02 * vm[10];
    float T10 = J11 * vm[4] + J12 * vm[8];
    float T11 = J11 * vm[5] + J12 * vm[9];
    float T12 = J11 * vm[6] + J12 * vm[10];

    float u00 = T00 * c00 + T01 * c01 + T02 * c02;
    float u01 = T00 * c01 + T01 * c11 + T02 * c12;
    float u02 = T00 * c02 + T01 * c12 + T02 * c22;
    float u10 = T10 * c00 + T11 * c01 + T12 * c02;
    float u11 = T10 * c01 + T11 * c11 + T12 * c12;
    float u12 = T10 * c02 + T11 * c12 + T12 * c22;
    float a  = u00 * T00 + u01 * T01 + u02 * T02 + 0.3f;
    float bb = u00 * T10 + u01 * T11 + u02 * T12;
    float cc = u10 * T10 + u11 * T11 + u12 * T12 + 0.3f;

    float det = a * cc - bb * bb;
    bool det_ok = det > 0.0f;
    float inv_det = det_ok ? 1.0f / det : 0.0f;
    float conA = cc * inv_det, conB = -bb * inv_det, conC = a * inv_det;
    float mid = 0.5f * (a + cc);
    float lam1 = mid + sqrtf(fmaxf(0.1f, mid * mid - det));
    float radius = ceilf(3.0f * sqrtf(lam1));
    bool valid = depth_ok && det_ok;

    radii_out[i] = valid ? (float)(int)radius : 0.0f;

    GP g;
    if (valid) {
        g.px = px; g.py = py; g.ca = conA; g.cb = conB;
        g.cc = conC; g.op = ops[i];
        g.cr = cols[3 * i]; g.cg = cols[3 * i + 1]; g.cbl = cols[3 * i + 2];
        g.p0 = 0.f; g.p1 = 0.f; g.p2 = 0.f;
    } else {
        g.px = 0.f; g.py = 0.f; g.ca = 0.f; g.cb = 0.f;
        g.cc = 0.f; g.op = 0.f; g.cr = 0.f; g.cg = 0.f;
        g.cbl = 0.f; g.p0 = 0.f; g.p1 = 0.f; g.p2 = 0.f;
    }
    params[i] = g;

    // positive floats (and +inf) sort correctly by bit pattern; idx breaks ties (stable)
    unsigned int kb = valid ? __float_as_uint(t2) : 0x7f800000u;
    keys[i] = ((unsigned long long)kb << 32) | (unsigned int)i;
}

// rank-by-counting "sort": keys are unique, so rank(g) = #{h: key_h < key_g}
// is exactly the stable-argsort permutation. 64 blocks x 16 gaussians each;
// 16 threads per gaussian scan strided chunks (bank-conflict-free).
__global__ __launch_bounds__(256) void k_rank(
    const unsigned long long* __restrict__ keys,
    const float* __restrict__ pin, float* __restrict__ pout)
{
    __shared__ unsigned long long sk[PCNT];
    __shared__ int srank[16];
    int t = threadIdx.x;
    #pragma unroll
    for (int i = 0; i < PCNT / 256; ++i) sk[t + i * 256] = keys[t + i * 256];
    __syncthreads();

    int gl = t >> 4;              // 0..15 local gaussian
    int j  = t & 15;              // chunk id
    int g  = blockIdx.x * 16 + gl;
    unsigned long long mykey = sk[g];
    int cnt = 0;
    #pragma unroll 8
    for (int k = 0; k < 64; ++k)
        cnt += (sk[j + (k << 4)] < mykey) ? 1 : 0;
    // reduce within the 16-lane group
    cnt += __shfl_xor(cnt, 1, 16);
    cnt += __shfl_xor(cnt, 2, 16);
    cnt += __shfl_xor(cnt, 4, 16);
    cnt += __shfl_xor(cnt, 8, 16);
    if (j == 0) srank[gl] = cnt;
    __syncthreads();

    // scatter: 16 gaussians x 12 floats
    if (t < 16 * 12) {
        int gl2 = t / 12, f = t % 12;
        int r = srank[gl2];
        pout[r * 12 + f] = pin[(blockIdx.x * 16 + gl2) * 12 + f];
    }
}

// Fused render: block = 1024 threads (16 waves), 64 pixels per block.
// Wave w composites segment w (64 sorted gaussians) for all 64 pixels
// (lane = pixel); partials combined in order via LDS by wave 0.
__global__ __launch_bounds__(1024) void k_render(
    const float4* __restrict__ sorted, const float* __restrict__ bg,
    float* __restrict__ out)
{
    __shared__ float4 sp[PCNT * 3];     // 48 KB
    __shared__ float4 part[SEG * 64];   // 16 KB
    int t = threadIdx.x;
    #pragma unroll
    for (int i = 0; i < 3; ++i) sp[t + i * 1024] = sorted[t + i * 1024];
    __syncthreads();

    int wave = t >> 6;
    int lane = t & 63;
    int pix = blockIdx.x * 64 + lane;
    float fxp = (float)(pix % WW);
    float fyp = (float)(pix / WW);

    float T = 1.0f, C0 = 0.f, C1 = 0.f, C2 = 0.f;
    int gbase = wave * GPSEG;
    #pragma unroll 4
    for (int g = gbase; g < gbase + GPSEG; ++g) {
        float4 v0 = sp[3 * g + 0];   // px,py,ca,cb
        float4 v1 = sp[3 * g + 1];   // cc,op,r,g
        float4 v2 = sp[3 * g + 2];   // b,-,-,-
        float dx = v0.x - fxp, dy = v0.y - fyp;
        float power = -0.5f * (v0.z * dx * dx + v1.x * dy * dy) - v0.w * dx * dy;
        float alpha = fminf(0.99f, v1.y * expf(power));
        if (power > 0.0f || alpha < (1.0f / 255.0f)) alpha = 0.0f;
        float w = alpha * T;
        C0 = fmaf(w, v1.z, C0);
        C1 = fmaf(w, v1.w, C1);
        C2 = fmaf(w, v2.x, C2);
        T *= (1.0f - alpha);
    }
    part[wave * 64 + lane] = make_float4(C0, C1, C2, T);
    __syncthreads();

    if (t < 64) {
        float Tt = 1.0f, c0 = 0.f, c1 = 0.f, c2 = 0.f;
        #pragma unroll
        for (int s = 0; s < SEG; ++s) {
            float4 v = part[s * 64 + t];
            c0 = fmaf(Tt, v.x, c0);
            c1 = fmaf(Tt, v.y, c1);
            c2 = fmaf(Tt, v.z, c2);
            Tt *= v.w;
        }
        int p2 = blockIdx.x * 64 + t;
        out[p2]             = c0 + Tt * bg[0];
        out[NPIX + p2]      = c1 + Tt * bg[1];
        out[2 * NPIX + p2]  = c2 + Tt * bg[2];
    }
}

extern "C" void kernel_launch(void* const* d_in, const int* in_sizes, int n_in,
                              void* d_out, int out_size, void* d_ws, size_t ws_size,
                              hipStream_t stream) {
    const float* means  = (const float*)d_in[0];
    const float* cols   = (const float*)d_in[2];
    const float* ops    = (const float*)d_in[3];
    const float* scales = (const float*)d_in[4];
    const float* rots   = (const float*)d_in[5];
    const float* bg     = (const float*)d_in[6];
    const float* vm     = (const float*)d_in[7];
    const float* pm     = (const float*)d_in[8];

    float* out = (float*)d_out;   // [3*NPIX color][PCNT radii-as-float]

    GP* params  = (GP*)d_ws;                                          // PCNT*48B
    GP* sortedp = params + PCNT;                                      // PCNT*48B
    unsigned long long* keys = (unsigned long long*)(sortedp + PCNT); // PCNT*8B

    k_pre<<<PCNT / 256, 256, 0, stream>>>(means, cols, ops, scales, rots, vm, pm,
                                          out + 3 * NPIX, params, keys);
    k_rank<<<PCNT / 16, 256, 0, stream>>>(keys, (const float*)params, (float*)sortedp);
    k_render<<<NPIX / 64, 1024, 0, stream>>>((const float4*)sortedp, bg, out);
}

// Round 4
// 30.842 us; speedup vs baseline: 3.4798x; 1.3697x over previous
//
#include <hip/hip_runtime.h>
#include <math.h>

#define PCNT 1024
#define HH 160
#define WW 160
#define NPIX (HH * WW)
#define SEG 16
#define GPSEG (PCNT / SEG)   // 64 gaussians per segment
#define PPB 128              // pixels per render block (2 per lane)

// 12 floats per gaussian: {px,py,ca',cb'}, {cc',op,r,g}, {b,0,0,0}
// ca',cb',cc' are pre-scaled by 0.5*log2(e) / log2(e) so power is in log2 domain.
struct __align__(16) GP {
    float px, py, ca, cb;
    float cc, op, cr, cg;
    float cbl, p0, p1, p2;
};

__global__ __launch_bounds__(256) void k_pre(
    const float* __restrict__ means, const float* __restrict__ cols,
    const float* __restrict__ ops, const float* __restrict__ scales,
    const float* __restrict__ rots, const float* __restrict__ vm,
    const float* __restrict__ pm, float* __restrict__ radii_out,
    GP* __restrict__ params, unsigned long long* __restrict__ keys)
{
    int i = blockIdx.x * blockDim.x + threadIdx.x;
    if (i >= PCNT) return;

    float mx = means[3 * i], my = means[3 * i + 1], mz = means[3 * i + 2];

    float t0 = vm[0] * mx + vm[1] * my + vm[2] * mz + vm[3];
    float t1 = vm[4] * mx + vm[5] * my + vm[6] * mz + vm[7];
    float t2 = vm[8] * mx + vm[9] * my + vm[10] * mz + vm[11];
    bool depth_ok = t2 > 0.2f;

    float ph0 = pm[0] * mx + pm[1] * my + pm[2] * mz + pm[3];
    float ph1 = pm[4] * mx + pm[5] * my + pm[6] * mz + pm[7];
    float ph3 = pm[12] * mx + pm[13] * my + pm[14] * mz + pm[15];
    float pw = 1.0f / (ph3 + 1e-7f);
    float px = ((ph0 * pw + 1.0f) * (float)WW - 1.0f) * 0.5f;
    float py = ((ph1 * pw + 1.0f) * (float)HH - 1.0f) * 0.5f;

    float qr = rots[4 * i], qx = rots[4 * i + 1], qy = rots[4 * i + 2], qz = rots[4 * i + 3];
    float R00 = 1.f - 2.f * (qy * qy + qz * qz), R01 = 2.f * (qx * qy - qr * qz), R02 = 2.f * (qx * qz + qr * qy);
    float R10 = 2.f * (qx * qy + qr * qz), R11 = 1.f - 2.f * (qx * qx + qz * qz), R12 = 2.f * (qy * qz - qr * qx);
    float R20 = 2.f * (qx * qz - qr * qy), R21 = 2.f * (qy * qz + qr * qx), R22 = 1.f - 2.f * (qx * qx + qy * qy);

    float s0 = scales[3 * i], s1 = scales[3 * i + 1], s2 = scales[3 * i + 2];
    float M00 = R00 * s0, M01 = R01 * s1, M02 = R02 * s2;
    float M10 = R10 * s0, M11 = R11 * s1, M12 = R12 * s2;
    float M20 = R20 * s0, M21 = R21 * s1, M22 = R22 * s2;
    float c00 = M00 * M00 + M01 * M01 + M02 * M02;
    float c01 = M00 * M10 + M01 * M11 + M02 * M12;
    float c02 = M00 * M20 + M01 * M21 + M02 * M22;
    float c11 = M10 * M10 + M11 * M11 + M12 * M12;
    float c12 = M10 * M20 + M11 * M21 + M12 * M22;
    float c22 = M20 * M20 + M21 * M21 + M22 * M22;

    const float fx = 160.0f, fy = 160.0f;
    const float limx = 0.65f, limy = 0.65f;
    float txz = fminf(limx, fmaxf(-limx, t0 / t2)) * t2;
    float tyz = fminf(limy, fmaxf(-limy, t1 / t2)) * t2;
    float J00 = fx / t2, J02 = -fx * txz / (t2 * t2);
    float J11 = fy / t2, J12 = -fy * tyz / (t2 * t2);

    float T00 = J00 * vm[0] + J02 * vm[8];
    float T01 = J00 * vm[1] + J02 * vm[9];
    float T02 = J00 * vm[2] + J02 * vm[10];
    float T10 = J11 * vm[4] + J12 * vm[8];
    float T11 = J11 * vm[5] + J12 * vm[9];
    float T12 = J11 * vm[6] + J12 * vm[10];

    float u00 = T00 * c00 + T01 * c01 + T02 * c02;
    float u01 = T00 * c01 + T01 * c11 + T02 * c12;
    float u02 = T00 * c02 + T01 * c12 + T02 * c22;
    float u10 = T10 * c00 + T11 * c01 + T12 * c02;
    float u11 = T10 * c01 + T11 * c11 + T12 * c12;
    float u12 = T10 * c02 + T11 * c12 + T12 * c22;
    float a  = u00 * T00 + u01 * T01 + u02 * T02 + 0.3f;
    float bb = u00 * T10 + u01 * T11 + u02 * T12;
    float cc = u10 * T10 + u11 * T11 + u12 * T12 + 0.3f;

    float det = a * cc - bb * bb;
    bool det_ok = det > 0.0f;
    float inv_det = det_ok ? 1.0f / det : 0.0f;
    float conA = cc * inv_det, conB = -bb * inv_det, conC = a * inv_det;
    float mid = 0.5f * (a + cc);
    float lam1 = mid + sqrtf(fmaxf(0.1f, mid * mid - det));
    float radius = ceilf(3.0f * sqrtf(lam1));
    bool valid = depth_ok && det_ok;

    radii_out[i] = valid ? (float)(int)radius : 0.0f;

    const float HL2E = 0.72134752044448170f;  // 0.5*log2(e)
    const float L2E  = 1.4426950408889634f;   // log2(e)

    GP g;
    if (valid) {
        g.px = px; g.py = py; g.ca = conA * HL2E; g.cb = conB * L2E;
        g.cc = conC * HL2E; g.op = ops[i];
        g.cr = cols[3 * i]; g.cg = cols[3 * i + 1]; g.cbl = cols[3 * i + 2];
        g.p0 = 0.f; g.p1 = 0.f; g.p2 = 0.f;
    } else {
        g.px = 0.f; g.py = 0.f; g.ca = 0.f; g.cb = 0.f;
        g.cc = 0.f; g.op = 0.f; g.cr = 0.f; g.cg = 0.f;
        g.cbl = 0.f; g.p0 = 0.f; g.p1 = 0.f; g.p2 = 0.f;
    }
    params[i] = g;

    // positive floats (and +inf) sort correctly by bit pattern; idx breaks ties (stable)
    unsigned int kb = valid ? __float_as_uint(t2) : 0x7f800000u;
    keys[i] = ((unsigned long long)kb << 32) | (unsigned int)i;
}

// rank-by-counting "sort": keys unique -> rank(g) = #{h: key_h < key_g}
__global__ __launch_bounds__(256) void k_rank(
    const unsigned long long* __restrict__ keys,
    const float* __restrict__ pin, float* __restrict__ pout)
{
    __shared__ unsigned long long sk[PCNT];
    __shared__ int srank[16];
    int t = threadIdx.x;
    #pragma unroll
    for (int i = 0; i < PCNT / 256; ++i) sk[t + i * 256] = keys[t + i * 256];
    __syncthreads();

    int gl = t >> 4;
    int j  = t & 15;
    int g  = blockIdx.x * 16 + gl;
    unsigned long long mykey = sk[g];
    int cnt = 0;
    #pragma unroll 8
    for (int k = 0; k < 64; ++k)
        cnt += (sk[j + (k << 4)] < mykey) ? 1 : 0;
    cnt += __shfl_xor(cnt, 1, 16);
    cnt += __shfl_xor(cnt, 2, 16);
    cnt += __shfl_xor(cnt, 4, 16);
    cnt += __shfl_xor(cnt, 8, 16);
    if (j == 0) srank[gl] = cnt;
    __syncthreads();

    if (t < 16 * 12) {
        int gl2 = t / 12, f = t % 12;
        int r = srank[gl2];
        pout[r * 12 + f] = pin[(blockIdx.x * 16 + gl2) * 12 + f];
    }
}

// Fused render: block = 1024 threads (16 waves), 128 pixels (2 per lane).
// Wave w composites segment w; gaussian params read via wave-uniform loads
// (L2-resident 48KB table) -- no LDS on the hot path.
__global__ __launch_bounds__(1024, 4) void k_render(
    const float4* __restrict__ sorted, const float* __restrict__ bg,
    float* __restrict__ out)
{
    __shared__ float4 part[SEG * PPB];   // 32 KB
    int t = threadIdx.x;
    int wave = t >> 6;
    int lane = t & 63;
    int wv = __builtin_amdgcn_readfirstlane(wave);  // force SGPR base
    const float4* gp = sorted + wv * (GPSEG * 3);

    int pixA = blockIdx.x * PPB + lane;
    int pixB = pixA + 64;
    float fxA = (float)(pixA % WW), fyA = (float)(pixA / WW);
    float fxB = (float)(pixB % WW), fyB = (float)(pixB / WW);

    float TA = 1.0f, A0 = 0.f, A1 = 0.f, A2 = 0.f;
    float TB = 1.0f, B0 = 0.f, B1 = 0.f, B2 = 0.f;
    #pragma unroll 4
    for (int g = 0; g < GPSEG; ++g) {
        float4 v0 = gp[3 * g + 0];   // px,py,ca',cb'
        float4 v1 = gp[3 * g + 1];   // cc',op,r,g
        float4 v2 = gp[3 * g + 2];   // b,-,-,-

        float dxA = v0.x - fxA, dyA = v0.y - fyA;
        float pA = -(v0.z * dxA * dxA + v1.x * dyA * dyA) - v0.w * dxA * dyA;
        float eA; asm("v_exp_f32 %0, %1" : "=v"(eA) : "v"(pA));
        float aA = fminf(0.99f, v1.y * eA);
        if (pA > 0.0f || aA < (1.0f / 255.0f)) aA = 0.0f;
        float wA = aA * TA;
        A0 = fmaf(wA, v1.z, A0);
        A1 = fmaf(wA, v1.w, A1);
        A2 = fmaf(wA, v2.x, A2);
        TA *= (1.0f - aA);

        float dxB = v0.x - fxB, dyB = v0.y - fyB;
        float pB = -(v0.z * dxB * dxB + v1.x * dyB * dyB) - v0.w * dxB * dyB;
        float eB; asm("v_exp_f32 %0, %1" : "=v"(eB) : "v"(pB));
        float aB = fminf(0.99f, v1.y * eB);
        if (pB > 0.0f || aB < (1.0f / 255.0f)) aB = 0.0f;
        float wB = aB * TB;
        B0 = fmaf(wB, v1.z, B0);
        B1 = fmaf(wB, v1.w, B1);
        B2 = fmaf(wB, v2.x, B2);
        TB *= (1.0f - aB);
    }
    part[wave * PPB + lane]      = make_float4(A0, A1, A2, TA);
    part[wave * PPB + 64 + lane] = make_float4(B0, B1, B2, TB);
    __syncthreads();

    if (t < PPB) {
        float Tt = 1.0f, c0 = 0.f, c1 = 0.f, c2 = 0.f;
        #pragma unroll
        for (int s = 0; s < SEG; ++s) {
            float4 v = part[s * PPB + t];
            c0 = fmaf(Tt, v.x, c0);
            c1 = fmaf(Tt, v.y, c1);
            c2 = fmaf(Tt, v.z, c2);
            Tt *= v.w;
        }
        int p2 = blockIdx.x * PPB + t;
        out[p2]            = c0 + Tt * bg[0];
        out[NPIX + p2]     = c1 + Tt * bg[1];
        out[2 * NPIX + p2] = c2 + Tt * bg[2];
    }
}

extern "C" void kernel_launch(void* const* d_in, const int* in_sizes, int n_in,
                              void* d_out, int out_size, void* d_ws, size_t ws_size,
                              hipStream_t stream) {
    const float* means  = (const float*)d_in[0];
    const float* cols   = (const float*)d_in[2];
    const float* ops    = (const float*)d_in[3];
    const float* scales = (const float*)d_in[4];
    const float* rots   = (const float*)d_in[5];
    const float* bg     = (const float*)d_in[6];
    const float* vm     = (const float*)d_in[7];
    const float* pm     = (const float*)d_in[8];

    float* out = (float*)d_out;   // [3*NPIX color][PCNT radii-as-float]

    GP* params  = (GP*)d_ws;                                          // PCNT*48B
    GP* sortedp = params + PCNT;                                      // PCNT*48B
    unsigned long long* keys = (unsigned long long*)(sortedp + PCNT); // PCNT*8B

    k_pre<<<PCNT / 256, 256, 0, stream>>>(means, cols, ops, scales, rots, vm, pm,
                                          out + 3 * NPIX, params, keys);
    k_rank<<<PCNT / 16, 256, 0, stream>>>(keys, (const float*)params, (float*)sortedp);
    k_render<<<NPIX / PPB, 1024, 0, stream>>>((const float4*)sortedp, bg, out);
}

// Round 5
// 29.150 us; speedup vs baseline: 3.6817x; 1.0580x over previous
//
#include <hip/hip_runtime.h>
#include <math.h>

#define PCNT 1024
#define HH 160
#define WW 160
#define NPIX (HH * WW)
#define TILE 8
#define TX (WW / TILE)       // 20
#define TY (HH / TILE)       // 20
#define NTILES (TX * TY)     // 400

// sorted params: 3 x float4 per gaussian: {px,py,ca',cb'}, {cc',op,r,g}, {b,0,0,0}
// ca',cb',cc' pre-scaled by 0.5*log2(e) / log2(e) (power in log2 domain).
// separate cull table: {px,py,hx,hy} per gaussian.

__global__ __launch_bounds__(256) void k_pre(
    const float* __restrict__ means, const float* __restrict__ cols,
    const float* __restrict__ ops, const float* __restrict__ scales,
    const float* __restrict__ rots, const float* __restrict__ vm,
    const float* __restrict__ pm, float* __restrict__ radii_out,
    float4* __restrict__ params16, unsigned long long* __restrict__ keys)
{
    int i = blockIdx.x * blockDim.x + threadIdx.x;
    if (i >= PCNT) return;

    float mx = means[3 * i], my = means[3 * i + 1], mz = means[3 * i + 2];

    float t0 = vm[0] * mx + vm[1] * my + vm[2] * mz + vm[3];
    float t1 = vm[4] * mx + vm[5] * my + vm[6] * mz + vm[7];
    float t2 = vm[8] * mx + vm[9] * my + vm[10] * mz + vm[11];
    bool depth_ok = t2 > 0.2f;

    float ph0 = pm[0] * mx + pm[1] * my + pm[2] * mz + pm[3];
    float ph1 = pm[4] * mx + pm[5] * my + pm[6] * mz + pm[7];
    float ph3 = pm[12] * mx + pm[13] * my + pm[14] * mz + pm[15];
    float pw = 1.0f / (ph3 + 1e-7f);
    float px = ((ph0 * pw + 1.0f) * (float)WW - 1.0f) * 0.5f;
    float py = ((ph1 * pw + 1.0f) * (float)HH - 1.0f) * 0.5f;

    float qr = rots[4 * i], qx = rots[4 * i + 1], qy = rots[4 * i + 2], qz = rots[4 * i + 3];
    float R00 = 1.f - 2.f * (qy * qy + qz * qz), R01 = 2.f * (qx * qy - qr * qz), R02 = 2.f * (qx * qz + qr * qy);
    float R10 = 2.f * (qx * qy + qr * qz), R11 = 1.f - 2.f * (qx * qx + qz * qz), R12 = 2.f * (qy * qz - qr * qx);
    float R20 = 2.f * (qx * qz - qr * qy), R21 = 2.f * (qy * qz + qr * qx), R22 = 1.f - 2.f * (qx * qx + qy * qy);

    float s0 = scales[3 * i], s1 = scales[3 * i + 1], s2 = scales[3 * i + 2];
    float M00 = R00 * s0, M01 = R01 * s1, M02 = R02 * s2;
    float M10 = R10 * s0, M11 = R11 * s1, M12 = R12 * s2;
    float M20 = R20 * s0, M21 = R21 * s1, M22 = R22 * s2;
    float c00 = M00 * M00 + M01 * M01 + M02 * M02;
    float c01 = M00 * M10 + M01 * M11 + M02 * M12;
    float c02 = M00 * M20 + M01 * M21 + M02 * M22;
    float c11 = M10 * M10 + M11 * M11 + M12 * M12;
    float c12 = M10 * M20 + M11 * M21 + M12 * M22;
    float c22 = M20 * M20 + M21 * M21 + M22 * M22;

    const float fx = 160.0f, fy = 160.0f;
    const float limx = 0.65f, limy = 0.65f;
    float txz = fminf(limx, fmaxf(-limx, t0 / t2)) * t2;
    float tyz = fminf(limy, fmaxf(-limy, t1 / t2)) * t2;
    float J00 = fx / t2, J02 = -fx * txz / (t2 * t2);
    float J11 = fy / t2, J12 = -fy * tyz / (t2 * t2);

    float T00 = J00 * vm[0] + J02 * vm[8];
    float T01 = J00 * vm[1] + J02 * vm[9];
    float T02 = J00 * vm[2] + J02 * vm[10];
    float T10 = J11 * vm[4] + J12 * vm[8];
    float T11 = J11 * vm[5] + J12 * vm[9];
    float T12 = J11 * vm[6] + J12 * vm[10];

    float u00 = T00 * c00 + T01 * c01 + T02 * c02;
    float u01 = T00 * c01 + T01 * c11 + T02 * c12;
    float u02 = T00 * c02 + T01 * c12 + T02 * c22;
    float u10 = T10 * c00 + T11 * c01 + T12 * c02;
    float u11 = T10 * c01 + T11 * c11 + T12 * c12;
    float u12 = T10 * c02 + T11 * c12 + T12 * c22;
    float a  = u00 * T00 + u01 * T01 + u02 * T02 + 0.3f;
    float bb = u00 * T10 + u01 * T11 + u02 * T12;
    float cc = u10 * T10 + u11 * T11 + u12 * T12 + 0.3f;

    float det = a * cc - bb * bb;
    bool det_ok = det > 0.0f;
    float inv_det = det_ok ? 1.0f / det : 0.0f;
    float conA = cc * inv_det, conB = -bb * inv_det, conC = a * inv_det;
    float mid = 0.5f * (a + cc);
    float lam1 = mid + sqrtf(fmaxf(0.1f, mid * mid - det));
    float radius = ceilf(3.0f * sqrtf(lam1));
    bool valid = depth_ok && det_ok;

    radii_out[i] = valid ? (float)(int)radius : 0.0f;

    const float HL2E = 0.72134752044448170f;  // 0.5*log2(e)
    const float L2E  = 1.4426950408889634f;   // log2(e)

    float4 v0, v1, v2, v3;
    if (valid) {
        float op = ops[i];
        // contribution is exactly 0 unless Q <= tau (alpha >= 1/255);
        // bounding half-widths of {Q<=tau}: hx=sqrt(2*tau*a), hy=sqrt(2*tau*c).
        float tau = fmaxf(logf(255.0f * op) + 0.02f, 0.0f);
        float hx = sqrtf(2.0f * tau * a);
        float hy = sqrtf(2.0f * tau * cc);
        v0 = make_float4(px, py, conA * HL2E, conB * L2E);
        v1 = make_float4(conC * HL2E, op, cols[3 * i], cols[3 * i + 1]);
        v2 = make_float4(cols[3 * i + 2], 0.f, 0.f, 0.f);
        v3 = make_float4(px, py, hx, hy);
    } else {
        v0 = make_float4(0.f, 0.f, 0.f, 0.f);
        v1 = v0; v2 = v0;
        v3 = make_float4(0.f, 0.f, -1e9f, -1e9f);   // never overlaps any tile
    }
    params16[i * 4 + 0] = v0;
    params16[i * 4 + 1] = v1;
    params16[i * 4 + 2] = v2;
    params16[i * 4 + 3] = v3;

    unsigned int kb = valid ? __float_as_uint(t2) : 0x7f800000u;
    keys[i] = ((unsigned long long)kb << 32) | (unsigned int)i;
}

// rank-by-counting "sort": keys unique -> rank(g) = #{h: key_h < key_g}.
// Scatters 12-float params to sortedp[rank] and 4-float cull to cull[rank].
__global__ __launch_bounds__(256) void k_rank(
    const unsigned long long* __restrict__ keys,
    const float* __restrict__ pin, float* __restrict__ pout,
    float* __restrict__ cull)
{
    __shared__ unsigned long long sk[PCNT];
    __shared__ int srank[16];
    int t = threadIdx.x;
    #pragma unroll
    for (int i = 0; i < PCNT / 256; ++i) sk[t + i * 256] = keys[t + i * 256];
    __syncthreads();

    int gl = t >> 4;
    int j  = t & 15;
    int g  = blockIdx.x * 16 + gl;
    unsigned long long mykey = sk[g];
    int cnt = 0;
    #pragma unroll 8
    for (int k = 0; k < 64; ++k)
        cnt += (sk[j + (k << 4)] < mykey) ? 1 : 0;
    cnt += __shfl_xor(cnt, 1, 16);
    cnt += __shfl_xor(cnt, 2, 16);
    cnt += __shfl_xor(cnt, 4, 16);
    cnt += __shfl_xor(cnt, 8, 16);
    if (j == 0) srank[gl] = cnt;
    __syncthreads();

    // 16 gaussians x 16 floats; f<12 -> params, f>=12 -> cull
    int gl2 = t >> 4, f = t & 15;
    int r = srank[gl2];
    float v = pin[(blockIdx.x * 16 + gl2) * 16 + f];
    if (f < 12) pout[r * 12 + f] = v;
    else        cull[r * 4 + (f - 12)] = v;
}

// One block = one 8x8 tile, 64 threads (1 wave, wave-synchronous).
// Phase 1: ordered ballot-compaction of depth-sorted gaussians overlapping
// this tile. Phase 2: chunked LDS staging + front-to-back composite.
__global__ __launch_bounds__(64) void k_render(
    const float4* __restrict__ sortedp, const float4* __restrict__ cull,
    const float* __restrict__ bg, float* __restrict__ out)
{
    __shared__ unsigned short list[PCNT];   // 2 KB
    __shared__ float4 stage[64 * 3];        // 3 KB

    int lane = threadIdx.x;
    int tx = blockIdx.x % TX, ty = blockIdx.x / TX;
    float x0 = (float)(tx * TILE), y0 = (float)(ty * TILE);

    // Phase 1: build ordered per-tile list
    int n = 0;
    #pragma unroll 4
    for (int k = 0; k < PCNT / 64; ++k) {
        float4 cv = cull[k * 64 + lane];    // px,py,hx,hy (depth-sorted)
        bool ov = (cv.x + cv.z >= x0 - 1.0f) & (cv.x - cv.z <= x0 + (float)TILE) &
                  (cv.y + cv.w >= y0 - 1.0f) & (cv.y - cv.w <= y0 + (float)TILE);
        unsigned long long mask = __ballot(ov);
        if (ov) list[n + __popcll(mask & ((1ull << lane) - 1ull))] =
                    (unsigned short)(k * 64 + lane);
        n += __popcll(mask);
    }

    float fxp = x0 + (float)(lane & 7);
    float fyp = y0 + (float)(lane >> 3);

    float T = 1.0f, C0 = 0.f, C1 = 0.f, C2 = 0.f;
    for (int base = 0; base < n; base += 64) {
        int m = min(64, n - base);
        __syncthreads();                    // stage reusable (prev chunk done)
        if (lane < m) {
            int idx = list[base + lane];
            stage[lane * 3 + 0] = sortedp[idx * 3 + 0];
            stage[lane * 3 + 1] = sortedp[idx * 3 + 1];
            stage[lane * 3 + 2] = sortedp[idx * 3 + 2];
        }
        __syncthreads();
        #pragma unroll 4
        for (int i = 0; i < m; ++i) {
            float4 v0 = stage[3 * i + 0];   // px,py,ca',cb'
            float4 v1 = stage[3 * i + 1];   // cc',op,r,g
            float4 v2 = stage[3 * i + 2];   // b,-,-,-
            float dx = v0.x - fxp, dy = v0.y - fyp;
            float p = -(v0.z * dx * dx + v1.x * dy * dy) - v0.w * dx * dy;
            float e; asm("v_exp_f32 %0, %1" : "=v"(e) : "v"(p));
            float al = fminf(0.99f, v1.y * e);
            if (p > 0.0f || al < (1.0f / 255.0f)) al = 0.0f;
            float w = al * T;
            C0 = fmaf(w, v1.z, C0);
            C1 = fmaf(w, v1.w, C1);
            C2 = fmaf(w, v2.x, C2);
            T *= (1.0f - al);
        }
    }

    int pix = ((int)fyp) * WW + (int)fxp;
    out[pix]            = C0 + T * bg[0];
    out[NPIX + pix]     = C1 + T * bg[1];
    out[2 * NPIX + pix] = C2 + T * bg[2];
}

extern "C" void kernel_launch(void* const* d_in, const int* in_sizes, int n_in,
                              void* d_out, int out_size, void* d_ws, size_t ws_size,
                              hipStream_t stream) {
    const float* means  = (const float*)d_in[0];
    const float* cols   = (const float*)d_in[2];
    const float* ops    = (const float*)d_in[3];
    const float* scales = (const float*)d_in[4];
    const float* rots   = (const float*)d_in[5];
    const float* bg     = (const float*)d_in[6];
    const float* vm     = (const float*)d_in[7];
    const float* pm     = (const float*)d_in[8];

    float* out = (float*)d_out;   // [3*NPIX color][PCNT radii-as-float]

    float4* params16 = (float4*)d_ws;                         // PCNT*64B
    float*  sortedp  = (float*)(params16 + PCNT * 4);         // PCNT*48B
    float*  cullt    = sortedp + PCNT * 12;                   // PCNT*16B
    unsigned long long* keys = (unsigned long long*)(cullt + PCNT * 4); // PCNT*8B

    k_pre<<<PCNT / 256, 256, 0, stream>>>(means, cols, ops, scales, rots, vm, pm,
                                          out + 3 * NPIX, params16, keys);
    k_rank<<<PCNT / 16, 256, 0, stream>>>(keys, (const float*)params16, sortedp, cullt);
    k_render<<<NTILES, 64, 0, stream>>>((const float4*)sortedp, (const float4*)cullt,
                                        bg, out);
}